// Round 1
// baseline (91.146 us; speedup 1.0000x reference)
//
#include <hip/hip_runtime.h>
#include <hip/hip_bf16.h>

// Problem constants (fixed-shape problem)
constexpr int B_ = 8, C_ = 21, H_ = 512, W_ = 512;
constexpr int HW = H_ * W_;             // 262144
constexpr long long NPIX = (long long)B_ * HW;  // 2097152
constexpr int GROUPS = (int)(NPIX / 4); // 524288 float4-groups of pixels
constexpr int GROUPS_PER_B = HW / 4;    // 65536  (power of two)
constexpr float INV_N = 1.0f / (float)NPIX;

// ---------------- Kernel A: histogram + packed labels --------------------
__global__ __launch_bounds__(256) void bsl_hist_kernel(
    const float* __restrict__ target,
    unsigned* __restrict__ freq,      // [21] global counts (pre-zeroed)
    unsigned* __restrict__ labels4)   // [GROUPS] packed uchar4 labels
{
    __shared__ unsigned hist[4][C_];  // per-wave histograms
    const int tid = threadIdx.x;
    const int wave = tid >> 6;
    if (tid < 4 * C_) ((unsigned*)hist)[tid] = 0u;
    __syncthreads();

    const int g   = blockIdx.x * 256 + tid;        // one group per thread
    const int b   = g >> 16;                       // g / GROUPS_PER_B
    const int rem = g & (GROUPS_PER_B - 1);
    const float* tb = target + (size_t)b * C_ * HW + (size_t)rem * 4;

    int lx = 0, ly = 0, lz = 0, lw = 0;
    #pragma unroll
    for (int c = 0; c < C_; ++c) {
        float4 t = *(const float4*)(tb + (size_t)c * HW);
        if (t.x > 0.5f) lx = c;
        if (t.y > 0.5f) ly = c;
        if (t.z > 0.5f) lz = c;
        if (t.w > 0.5f) lw = c;
    }
    atomicAdd(&hist[wave][lx], 1u);
    atomicAdd(&hist[wave][ly], 1u);
    atomicAdd(&hist[wave][lz], 1u);
    atomicAdd(&hist[wave][lw], 1u);
    labels4[g] = (unsigned)lx | ((unsigned)ly << 8) | ((unsigned)lz << 16) | ((unsigned)lw << 24);

    __syncthreads();
    if (tid < C_) {
        unsigned s = hist[0][tid] + hist[1][tid] + hist[2][tid] + hist[3][tid];
        atomicAdd(&freq[tid], s);
    }
}

// ---------------- Kernel B: per-pixel balanced log-softmax + reduce ------
__global__ __launch_bounds__(256) void bsl_loss_kernel(
    const float* __restrict__ pred,
    const unsigned* __restrict__ freq,
    const unsigned* __restrict__ labels4,
    float* __restrict__ out)          // [1], pre-zeroed
{
    __shared__ float lf_s[C_];
    const int tid = threadIdx.x;
    if (tid < C_) lf_s[tid] = __logf((float)freq[tid]);
    __syncthreads();

    const int g   = blockIdx.x * 256 + tid;
    const int b   = g >> 16;
    const int rem = g & (GROUPS_PER_B - 1);
    const float* pb = pred + (size_t)b * C_ * HW + (size_t)rem * 4;

    const unsigned lab = labels4[g];
    const int lx = lab & 255, ly = (lab >> 8) & 255, lz = (lab >> 16) & 255, lw = lab >> 24;

    float4 vals[C_];
    float mx = -1e30f, my = -1e30f, mz = -1e30f, mw = -1e30f;
    float vlx = 0.f, vly = 0.f, vlz = 0.f, vlw = 0.f;

    #pragma unroll
    for (int c = 0; c < C_; ++c) {
        float4 p = *(const float4*)(pb + (size_t)c * HW);
        const float lf = lf_s[c];
        p.x += lf; p.y += lf; p.z += lf; p.w += lf;
        vals[c] = p;                        // statically indexed -> stays in VGPRs
        mx = fmaxf(mx, p.x); my = fmaxf(my, p.y);
        mz = fmaxf(mz, p.z); mw = fmaxf(mw, p.w);
        if (c == lx) vlx = p.x;
        if (c == ly) vly = p.y;
        if (c == lz) vlz = p.z;
        if (c == lw) vlw = p.w;
    }

    float sx = 0.f, sy = 0.f, sz = 0.f, sw = 0.f;
    #pragma unroll
    for (int c = 0; c < C_; ++c) {
        sx += __expf(vals[c].x - mx);
        sy += __expf(vals[c].y - my);
        sz += __expf(vals[c].z - mz);
        sw += __expf(vals[c].w - mw);
    }

    float term = (vlx - mx - __logf(sx)) + (vly - my - __logf(sy))
               + (vlz - mz - __logf(sz)) + (vlw - mw - __logf(sw));

    // block reduction: wave shuffle then LDS across 4 waves
    #pragma unroll
    for (int off = 32; off > 0; off >>= 1) term += __shfl_down(term, off, 64);
    __shared__ float wsum[4];
    if ((tid & 63) == 0) wsum[tid >> 6] = term;
    __syncthreads();
    if (tid == 0) {
        float bs = wsum[0] + wsum[1] + wsum[2] + wsum[3];
        atomicAdd(out, -bs * INV_N);
    }
}

// ---------------- Fallback (tiny ws): recompute labels from target -------
__global__ __launch_bounds__(256) void bsl_loss_fallback_kernel(
    const float* __restrict__ pred,
    const float* __restrict__ target,
    const unsigned* __restrict__ freq,
    float* __restrict__ out)
{
    __shared__ float lf_s[C_];
    const int tid = threadIdx.x;
    if (tid < C_) lf_s[tid] = __logf((float)freq[tid]);
    __syncthreads();

    const int g   = blockIdx.x * 256 + tid;
    const int b   = g >> 16;
    const int rem = g & (GROUPS_PER_B - 1);
    const size_t base = (size_t)b * C_ * HW + (size_t)rem * 4;
    const float* pb = pred + base;
    const float* tb = target + base;

    float4 vals[C_];
    float mx = -1e30f, my = -1e30f, mz = -1e30f, mw = -1e30f;
    float vlx = 0.f, vly = 0.f, vlz = 0.f, vlw = 0.f;

    #pragma unroll
    for (int c = 0; c < C_; ++c) {
        float4 p = *(const float4*)(pb + (size_t)c * HW);
        float4 t = *(const float4*)(tb + (size_t)c * HW);
        const float lf = lf_s[c];
        p.x += lf; p.y += lf; p.z += lf; p.w += lf;
        vals[c] = p;
        mx = fmaxf(mx, p.x); my = fmaxf(my, p.y);
        mz = fmaxf(mz, p.z); mw = fmaxf(mw, p.w);
        if (t.x > 0.5f) vlx = p.x;
        if (t.y > 0.5f) vly = p.y;
        if (t.z > 0.5f) vlz = p.z;
        if (t.w > 0.5f) vlw = p.w;
    }

    float sx = 0.f, sy = 0.f, sz = 0.f, sw = 0.f;
    #pragma unroll
    for (int c = 0; c < C_; ++c) {
        sx += __expf(vals[c].x - mx);
        sy += __expf(vals[c].y - my);
        sz += __expf(vals[c].z - mz);
        sw += __expf(vals[c].w - mw);
    }

    float term = (vlx - mx - __logf(sx)) + (vly - my - __logf(sy))
               + (vlz - mz - __logf(sz)) + (vlw - mw - __logf(sw));

    #pragma unroll
    for (int off = 32; off > 0; off >>= 1) term += __shfl_down(term, off, 64);
    __shared__ float wsum[4];
    if ((tid & 63) == 0) wsum[tid >> 6] = term;
    __syncthreads();
    if (tid == 0) {
        float bs = wsum[0] + wsum[1] + wsum[2] + wsum[3];
        atomicAdd(out, -bs * INV_N);
    }
}

// Fallback histogram (no label store)
__global__ __launch_bounds__(256) void bsl_hist_nolab_kernel(
    const float* __restrict__ target,
    unsigned* __restrict__ freq)
{
    __shared__ unsigned hist[4][C_];
    const int tid = threadIdx.x;
    const int wave = tid >> 6;
    if (tid < 4 * C_) ((unsigned*)hist)[tid] = 0u;
    __syncthreads();

    const int g   = blockIdx.x * 256 + tid;
    const int b   = g >> 16;
    const int rem = g & (GROUPS_PER_B - 1);
    const float* tb = target + (size_t)b * C_ * HW + (size_t)rem * 4;

    int lx = 0, ly = 0, lz = 0, lw = 0;
    #pragma unroll
    for (int c = 0; c < C_; ++c) {
        float4 t = *(const float4*)(tb + (size_t)c * HW);
        if (t.x > 0.5f) lx = c;
        if (t.y > 0.5f) ly = c;
        if (t.z > 0.5f) lz = c;
        if (t.w > 0.5f) lw = c;
    }
    atomicAdd(&hist[wave][lx], 1u);
    atomicAdd(&hist[wave][ly], 1u);
    atomicAdd(&hist[wave][lz], 1u);
    atomicAdd(&hist[wave][lw], 1u);

    __syncthreads();
    if (tid < C_) {
        unsigned s = hist[0][tid] + hist[1][tid] + hist[2][tid] + hist[3][tid];
        atomicAdd(&freq[tid], s);
    }
}

extern "C" void kernel_launch(void* const* d_in, const int* in_sizes, int n_in,
                              void* d_out, int out_size, void* d_ws, size_t ws_size,
                              hipStream_t stream) {
    const float* pred   = (const float*)d_in[0];
    const float* target = (const float*)d_in[1];
    float* out = (float*)d_out;

    // ws layout: [0..127] freq counters (21 x u32, padded), [128..] packed labels (GROUPS x u32)
    unsigned* freq    = (unsigned*)d_ws;
    unsigned* labels4 = (unsigned*)((char*)d_ws + 128);
    const size_t need = 128 + (size_t)GROUPS * sizeof(unsigned);

    // zero the accumulators every call (harness poisons once, never re-poisons)
    hipMemsetAsync(d_out, 0, sizeof(float), stream);
    hipMemsetAsync(d_ws, 0, 128, stream);

    const int blocks = GROUPS / 256;  // 2048, exact

    if (ws_size >= need) {
        bsl_hist_kernel<<<blocks, 256, 0, stream>>>(target, freq, labels4);
        bsl_loss_kernel<<<blocks, 256, 0, stream>>>(pred, freq, labels4, out);
    } else {
        bsl_hist_nolab_kernel<<<blocks, 256, 0, stream>>>(target, freq);
        bsl_loss_fallback_kernel<<<blocks, 256, 0, stream>>>(pred, target, freq, out);
    }
}